// Round 8
// baseline (208.245 us; speedup 1.0000x reference)
//
#include <hip/hip_runtime.h>
#include <hip/hip_bf16.h>
#include <stdint.h>

typedef __bf16 bf16;
typedef __bf16 bf16x8 __attribute__((ext_vector_type(8)));
typedef float f32x4 __attribute__((ext_vector_type(4)));

#define HIDDEN 1024
#define HEADS  16
#define HD     64
#define SEQ    2048
#define BATCH  2
#define NTOK   (BATCH*SEQ)
#define E3     (3*HIDDEN)

// softmax scale 1/8 with log2(e) folded in, applied to Q at QKV-GEMM epilogue
#define QSCALE (0.125f * 1.44269504088896f)

#if __has_builtin(__builtin_amdgcn_exp2f)
#define EXP2(x) __builtin_amdgcn_exp2f(x)
#else
#define EXP2(x) __expf((x) * 0.69314718055995f)
#endif

static __device__ __forceinline__ uint32_t pkbf(float a, float b) {
  union { bf16 h[2]; uint32_t u; } x;
  x.h[0] = (bf16)a; x.h[1] = (bf16)b;
  return x.u;
}

// ---------------- f32 -> bf16 convert of x, w_qkv, w_out ----------------
__global__ __launch_bounds__(256) void k_convert(
    const float* __restrict__ x, const float* __restrict__ wqkv, const float* __restrict__ wout,
    bf16* __restrict__ xb, bf16* __restrict__ wqkvb, bf16* __restrict__ woutb)
{
  const int NX = NTOK*HIDDEN/4, NW = E3*HIDDEN/4;
  int i = blockIdx.x*256 + threadIdx.x;
  const float4* s; bf16* d; int o;
  if (i < NX)            { s=(const float4*)x;    d=xb;    o=i; }
  else if (i < NX+NW)    { s=(const float4*)wqkv; d=wqkvb; o=i-NX; }
  else                   { s=(const float4*)wout; d=woutb; o=i-NX-NW; }
  float4 v = s[o];
  union { bf16 b[4]; uint2 u; } p;
  p.b[0]=(bf16)v.x; p.b[1]=(bf16)v.y; p.b[2]=(bf16)v.z; p.b[3]=(bf16)v.w;
  *(uint2*)(d + (size_t)o*4) = p.u;
}

// ---------------- bf16 GEMM  C[M,N] = A[M,K] * B[N,K]^T,  BK=32 ----------------
// Single-barrier double-buffered pipeline (T3-minimum): stage(next,buf^1) issued
// BEFORE ds_read(cur)+MFMA; one __syncthreads per K-step drains vmcnt+lgkm.
// EPI=0: scatter to Q/K/V head layout (Q scaled by QSCALE).  EPI=1: f32 out.
template<int EPI, int BM>
__global__ __launch_bounds__(256) void k_gemm(
    const bf16* __restrict__ A, const bf16* __restrict__ B,
    bf16* __restrict__ Oq, bf16* __restrict__ Ok, bf16* __restrict__ Ov,
    float* __restrict__ Of, int M, int N, int K, int nbn)
{
  constexpr int MI = BM/32;
  __shared__ bf16 As[2][BM*32];
  __shared__ bf16 Bs[2][128*32];
  const int t = threadIdx.x;
  const int lane = t & 63;
  const int w = t >> 6;
  const int g = lane >> 4;
  const int l15 = lane & 15;
  const int wm = (w >> 1) * (BM/2), wn = (w & 1) * 64;
  const int bm = blockIdx.x / nbn, bn = blockIdx.x % nbn;
  const int brow = bm*BM, bcol = bn*128;

  f32x4 acc[MI][4];
  #pragma unroll
  for (int mi=0;mi<MI;mi++)
    #pragma unroll
    for (int ni=0;ni<4;ni++)
      #pragma unroll
      for (int r=0;r<4;r++) acc[mi][ni][r] = 0.f;

  auto stage = [&](int kt, int buf) {
    // chunk ch -> row = ch>>2, part = ch&3 (16B); LDS linear
    if constexpr (BM == 128) {
      #pragma unroll
      for (int j=0;j<2;j++) {
        int ch = w*128 + j*64 + lane;
        const bf16* ga = A + (size_t)(brow + (ch>>2))*K + kt*32 + (ch&3)*8;
        __builtin_amdgcn_global_load_lds((const uint32_t*)ga,
            (uint32_t*)(&As[buf][0] + (size_t)(w*128 + j*64)*8), 16, 0, 0);
      }
    } else {
      int ch = w*64 + lane;
      const bf16* ga = A + (size_t)(brow + (ch>>2))*K + kt*32 + (ch&3)*8;
      __builtin_amdgcn_global_load_lds((const uint32_t*)ga,
          (uint32_t*)(&As[buf][0] + (size_t)(w*64)*8), 16, 0, 0);
    }
    #pragma unroll
    for (int j=0;j<2;j++) {
      int ch = w*128 + j*64 + lane;
      const bf16* gb = B + (size_t)(bcol + (ch>>2))*K + kt*32 + (ch&3)*8;
      __builtin_amdgcn_global_load_lds((const uint32_t*)gb,
          (uint32_t*)(&Bs[buf][0] + (size_t)(w*128 + j*64)*8), 16, 0, 0);
    }
  };

  const int nk = K >> 5;
  stage(0, 0);
  __syncthreads();
  for (int kt = 0; kt < nk; ++kt) {
    int cur = kt & 1;
    if (kt+1 < nk) stage(kt+1, cur^1);   // loads fly under this tile's compute
    bf16x8 af[MI], bfr[4];
    #pragma unroll
    for (int mi=0;mi<MI;mi++) af[mi]  = *(const bf16x8*)(&As[cur][0] + (wm + mi*16 + l15)*32 + g*8);
    #pragma unroll
    for (int ni=0;ni<4;ni++) bfr[ni] = *(const bf16x8*)(&Bs[cur][0] + (wn + ni*16 + l15)*32 + g*8);
    #pragma unroll
    for (int mi=0;mi<MI;mi++)
      #pragma unroll
      for (int ni=0;ni<4;ni++)
        acc[mi][ni] = __builtin_amdgcn_mfma_f32_16x16x32_bf16(af[mi], bfr[ni], acc[mi][ni], 0, 0, 0);
    __syncthreads();                     // drains vmcnt (next tile staged) + lgkm
  }

  #pragma unroll
  for (int mi=0;mi<MI;mi++) {
    #pragma unroll
    for (int ni=0;ni<4;ni++) {
      #pragma unroll
      for (int r=0;r<4;r++) {
        float val = acc[mi][ni][r];
        int m = brow + wm + mi*16 + 4*g + r;
        int e = bcol + wn + ni*16 + l15;
        if (EPI == 0) {
          int part = e >> 10, we = e & 1023;
          int hh = we >> 6, dd = we & 63;
          int b = m >> 11, sb = m & 2047;
          size_t idx = (((size_t)b*HEADS + hh)*SEQ + sb)*HD + dd;
          if (part == 0)      Oq[idx] = (bf16)(val * QSCALE);
          else if (part == 1) Ok[idx] = (bf16)val;
          else                Ov[idx] = (bf16)val;
        } else {
          Of[(size_t)m*HIDDEN + e] = val;
        }
      }
    }
  }
}

// ---------------- flash attention, 32 q-rows/wave, direct-L2 K reads ----------------
// grid: 32 bh * 16 qblocks; 4 waves/block. K fragments read straight from global
// (L2-resident, 16 blocks/bh reuse; m169: don't LDS-stage what L2 fits). Only V is
// LDS-staged (transposed, double-buffered, T14 early reg loads). ONE barrier/tile.
__global__ __launch_bounds__(256, 2) void k_attn(
    const bf16* __restrict__ Qg, const bf16* __restrict__ Kg, const bf16* __restrict__ Vg,
    bf16* __restrict__ Og)
{
  __shared__ bf16 Vt[2][64*64];   // [d][pos] 128B rows, pos = kv-permuted, XOR swizzle
  const int t = threadIdx.x;
  const int lane = t & 63;
  const int w = t >> 6;
  const int g = lane >> 4;      // 0..3
  const int q = lane & 15;      // this lane's q row (within 16-row q-set)
  const int bh = blockIdx.x >> 4;
  const int qb = blockIdx.x & 15;
  const int q0 = qb*128 + w*32;
  const size_t bhS = (size_t)bh * SEQ * HD;

  // Q fragments (B-operand): k-slot 8g+j of chunk kc -> d = 32kc + 8g + j
  bf16x8 qf[2][2];
  #pragma unroll
  for (int qs=0;qs<2;qs++) {
    const bf16* qrow = Qg + bhS + (size_t)(q0 + 16*qs + q)*HD + 8*g;
    qf[qs][0] = *(const bf16x8*)(qrow);
    qf[qs][1] = *(const bf16x8*)(qrow + 32);
  }

  f32x4 ot[2][4];              // O^T[d = 16df+4g+r][q], per q-set
  #pragma unroll
  for (int qs=0;qs<2;qs++)
    #pragma unroll
    for (int df=0;df<4;df++)
      #pragma unroll
      for (int r=0;r<4;r++) ot[qs][df][r] = 0.f;
  float mrun0 = -3.0e38f, mrun1 = -3.0e38f, lrun0 = 0.f, lrun1 = 0.f;

  // V staging: thread handles kv pair (kv0,kv0+1) x 8 d's; permuted column pos0
  const int kv0 = (t & 31)*2;
  const int dd0 = (t >> 5)*8;
  const int kvf0 = kv0 >> 4, gv = (kv0 >> 2) & 3, rv = kv0 & 3;
  const int pos0 = 32*(kvf0 >> 1) + 8*gv + 4*(kvf0 & 1) + rv;   // even

  auto loadV = [&](int it, uint4& a, uint4& b) {
    const bf16* vg = Vg + bhS + (size_t)(it*64 + kv0)*HD + dd0;
    a = *(const uint4*)vg;
    b = *(const uint4*)(vg + HD);
  };
  auto writeVt = [&](int buf, uint4 va, uint4 vb) {
    const uint32_t* pa = (const uint32_t*)&va;
    const uint32_t* pb = (const uint32_t*)&vb;
    char* base = (char*)&Vt[buf][0];
    #pragma unroll
    for (int jj=0;jj<8;jj++) {
      int dd = dd0 + jj;                       // dd&7 == jj
      uint32_t pr = __builtin_amdgcn_perm(pb[jj>>1], pa[jj>>1],
                                          (jj&1) ? 0x07060302u : 0x05040100u);
      int byte = (dd*128 + pos0*2) ^ (jj<<4);
      *(uint32_t*)(base + byte) = pr;
    }
  };

  uint4 va, vb;
  loadV(0, va, vb);
  writeVt(0, va, vb);
  __syncthreads();
  loadV(1, va, vb);            // T14: tile 1 regs in flight across tile 0 compute

  const int NT = SEQ/64;
  for (int it = 0; it < NT; ++it) {
    const int cur = it & 1;

    // ---- QK^T: K fragments direct from global (A-operand rows 16kvf+q, d 8g+32kc)
    bf16x8 kf[4][2];
    {
      const bf16* kbase = Kg + bhS + (size_t)(it*64 + q)*HD + 8*g;
      #pragma unroll
      for (int kvf=0;kvf<4;kvf++) {
        kf[kvf][0] = *(const bf16x8*)(kbase + (size_t)(16*kvf)*HD);
        kf[kvf][1] = *(const bf16x8*)(kbase + (size_t)(16*kvf)*HD + 32);
      }
    }
    f32x4 sf[2][4];
    #pragma unroll
    for (int qs=0;qs<2;qs++)
      #pragma unroll
      for (int kvf=0;kvf<4;kvf++)
        #pragma unroll
        for (int r=0;r<4;r++) sf[qs][kvf][r] = 0.f;
    __builtin_amdgcn_s_setprio(1);
    #pragma unroll
    for (int kvf=0;kvf<4;kvf++)
      #pragma unroll
      for (int kc=0;kc<2;kc++) {
        sf[0][kvf] = __builtin_amdgcn_mfma_f32_16x16x32_bf16(kf[kvf][kc], qf[0][kc], sf[0][kvf], 0,0,0);
        sf[1][kvf] = __builtin_amdgcn_mfma_f32_16x16x32_bf16(kf[kvf][kc], qf[1][kc], sf[1][kvf], 0,0,0);
      }
    __builtin_amdgcn_s_setprio(0);

    // ---- online softmax (log2 domain), two row-states per lane
    float pm0 = -3.0e38f, pm1 = -3.0e38f;
    #pragma unroll
    for (int kvf=0;kvf<4;kvf++)
      #pragma unroll
      for (int r=0;r<4;r++) {
        pm0 = fmaxf(pm0, sf[0][kvf][r]);
        pm1 = fmaxf(pm1, sf[1][kvf][r]);
      }
    pm0 = fmaxf(pm0, __shfl_xor(pm0, 16, 64));
    pm0 = fmaxf(pm0, __shfl_xor(pm0, 32, 64));
    pm1 = fmaxf(pm1, __shfl_xor(pm1, 16, 64));
    pm1 = fmaxf(pm1, __shfl_xor(pm1, 32, 64));

    bool need = (pm0 - mrun0 > 8.f) || (pm1 - mrun1 > 8.f);
    if (__any(need)) {           // defer-max: rescale only on significant growth
      float mn0 = fmaxf(mrun0, pm0), mn1 = fmaxf(mrun1, pm1);
      float a0 = EXP2(mrun0 - mn0), a1 = EXP2(mrun1 - mn1);
      lrun0 *= a0; lrun1 *= a1;
      #pragma unroll
      for (int df=0;df<4;df++)
        #pragma unroll
        for (int r=0;r<4;r++) { ot[0][df][r] *= a0; ot[1][df][r] *= a1; }
      mrun0 = mn0; mrun1 = mn1;
    }
    float rs0 = 0.f, rs1 = 0.f;
    #pragma unroll
    for (int kvf=0;kvf<4;kvf++)
      #pragma unroll
      for (int r=0;r<4;r++) {
        float p0 = EXP2(sf[0][kvf][r] - mrun0); sf[0][kvf][r] = p0; rs0 += p0;
        float p1 = EXP2(sf[1][kvf][r] - mrun1); sf[1][kvf][r] = p1; rs1 += p1;
      }
    rs0 += __shfl_xor(rs0, 16, 64); rs0 += __shfl_xor(rs0, 32, 64);
    rs1 += __shfl_xor(rs1, 16, 64); rs1 += __shfl_xor(rs1, 32, 64);
    lrun0 += rs0; lrun1 += rs1;

    // ---- pack P (lane-local B-fragments thanks to kv-slot permutation)
    uint32_t pk[2][4][2];
    #pragma unroll
    for (int qs=0;qs<2;qs++)
      #pragma unroll
      for (int kvf=0;kvf<4;kvf++) {
        pk[qs][kvf][0] = pkbf(sf[qs][kvf][0], sf[qs][kvf][1]);
        pk[qs][kvf][1] = pkbf(sf[qs][kvf][2], sf[qs][kvf][3]);
      }

    // ---- PV: O^T += V^T * P^T; each vf read feeds both q-sets
    __builtin_amdgcn_s_setprio(1);
    #pragma unroll
    for (int kc=0;kc<2;kc++) {
      union { uint32_t u[4]; bf16x8 v; } pf0, pf1;
      pf0.u[0] = pk[0][2*kc][0]; pf0.u[1] = pk[0][2*kc][1];
      pf0.u[2] = pk[0][2*kc+1][0]; pf0.u[3] = pk[0][2*kc+1][1];
      pf1.u[0] = pk[1][2*kc][0]; pf1.u[1] = pk[1][2*kc][1];
      pf1.u[2] = pk[1][2*kc+1][0]; pf1.u[3] = pk[1][2*kc+1][1];
      #pragma unroll
      for (int df=0;df<4;df++) {
        int row = 16*df + q;
        int byte = row*128 + ((16*g + 64*kc) ^ ((row&7)<<4));
        bf16x8 vf = *(const bf16x8*)((const char*)&Vt[cur][0] + byte);
        ot[0][df] = __builtin_amdgcn_mfma_f32_16x16x32_bf16(vf, pf0.v, ot[0][df], 0,0,0);
        ot[1][df] = __builtin_amdgcn_mfma_f32_16x16x32_bf16(vf, pf1.v, ot[1][df], 0,0,0);
      }
    }
    __builtin_amdgcn_s_setprio(0);

    // ---- stage tile it+1 into buf cur^1 (read in tile it-1; reads drained at
    // the barrier ending it-1), then ONE barrier; early-issue tile it+2 loads.
    if (it+1 < NT) writeVt(cur^1, va, vb);
    if (it+2 < NT) loadV(it+2, va, vb);
    __syncthreads();
  }

  // normalize + store O[token][head*64 + d], 8B per (qs,df)
  float inv0 = 1.0f / lrun0, inv1 = 1.0f / lrun1;
  int b = bh >> 4, head = bh & 15;
  #pragma unroll
  for (int qs=0;qs<2;qs++) {
    float inv = qs ? inv1 : inv0;
    size_t orow = ((size_t)b*SEQ + q0 + 16*qs + q)*HIDDEN + head*HD;
    #pragma unroll
    for (int df=0;df<4;df++) {
      uint2 pr;
      pr.x = pkbf(ot[qs][df][0]*inv, ot[qs][df][1]*inv);
      pr.y = pkbf(ot[qs][df][2]*inv, ot[qs][df][3]*inv);
      *(uint2*)(Og + orow + 16*df + 4*g) = pr;
    }
  }
}

extern "C" void kernel_launch(void* const* d_in, const int* in_sizes, int n_in,
                              void* d_out, int out_size, void* d_ws, size_t ws_size,
                              hipStream_t stream)
{
  (void)in_sizes; (void)n_in; (void)out_size; (void)ws_size;
  const float* x    = (const float*)d_in[0];
  const float* wqkv = (const float*)d_in[1];
  const float* wout = (const float*)d_in[2];
  float* out = (float*)d_out;
  char* ws = (char*)d_ws;
  bf16* xb    = (bf16*)(ws);                 //  8 MiB  [4096][1024]
  bf16* wqkvb = (bf16*)(ws + 8388608);       //  6 MiB  [3072][1024]
  bf16* woutb = (bf16*)(ws + 14680064);      //  2 MiB  [1024][1024]
  bf16* Q     = (bf16*)(ws + 16777216);      //  8 MiB  [2][16][2048][64] (pre-scaled QSCALE)
  bf16* K     = (bf16*)(ws + 25165824);      //  8 MiB
  bf16* V     = (bf16*)(ws + 33554432);      //  8 MiB
  bf16* O     = (bf16*)(ws + 41943040);      //  8 MiB  [4096][1024]

  k_convert<<<8192, 256, 0, stream>>>(x, wqkv, wout, xb, wqkvb, woutb);
  k_gemm<0,128><<<32*24, 256, 0, stream>>>(xb, wqkvb, Q, K, V, nullptr, NTOK, E3, HIDDEN, 24);
  k_attn<<<512, 256, 0, stream>>>(Q, K, V, O);
  k_gemm<1,64><<<64*8, 256, 0, stream>>>(O, woutb, nullptr, nullptr, nullptr, out, NTOK, HIDDEN, HIDDEN, 8);
}